// Round 2
// baseline (379.417 us; speedup 1.0000x reference)
//
#include <hip/hip_runtime.h>
#include <hip/hip_fp16.h>

#define NFEAT 64
#define SCAN_CHUNK 2048   // 256 threads x 8

typedef _Float16 half8 __attribute__((ext_vector_type(8)));
typedef float f32x4 __attribute__((ext_vector_type(4)));

// ---------------- async global->LDS helper (16B per lane, wave-uniform LDS base) ---
__device__ __forceinline__ void gll16(const float* g, float* l) {
    __builtin_amdgcn_global_load_lds(
        (const __attribute__((address_space(1))) unsigned int*)g,
        (__attribute__((address_space(3))) unsigned int*)l, 16, 0, 0);
}

__device__ __forceinline__ __half2 bch(unsigned int u) {
    return __builtin_bit_cast(__half2, u);
}

// ---------------- W transpose+convert: Wt[n][k] = fp16(W[k][n]) ----------------
__global__ void k_cvtW(const float* __restrict__ W, __half* __restrict__ Wt, int K) {
    int idx = blockIdx.x * 256 + threadIdx.x;
    if (idx >= 64 * K) return;
    int n = idx / K;
    int k = idx % K;
    Wt[idx] = __float2half(W[(size_t)k * NFEAT + n]);
}

// ---------------- FUSED: MFMA GEMM  +  degree-count/rank -----------------------
// CNT: odd blocks run the count path. Degree counts are XCD-SHARDED
// (counts8[xcd][node]) and incremented with WORKGROUP-scope atomics, which
// execute in the issuing XCD's L2 (no device-scope memory-side bypass).
// Sharding by the physical XCD id (s_getreg HW_REG_XCC_ID) makes same-L2
// execution correct: all updates to shard k come from XCD k's L2.
// This removes the ~49MB of per-atomic write-through (WRITE_SIZE evidence)
// and the ~600-900cy memory-side RMW latency that was the kernel's floor.
// rank[e] = (local_rank << 3) | xcd.
template<int K, bool SCALE, bool CNT>
__global__ __launch_bounds__(256) void k_gemm_x(
    const float* __restrict__ A, const __half* __restrict__ Wt,
    const float* __restrict__ dinv, __half* __restrict__ H, int M,
    const int* __restrict__ eiDst, int* __restrict__ counts,
    int* __restrict__ rank, int E)
{
    int tid = threadIdx.x;
    int gemmIdx;
    if (CNT) {
        int bid = blockIdx.x;
        if (bid & 1) {
            // ---- count path: 4 edges/thread, XCD-local atomics ----
            unsigned xcd;
            asm("s_getreg_b32 %0, hwreg(HW_REG_XCC_ID)" : "=s"(xcd));
            xcd &= 7;
            int* cb = counts + (size_t)xcd * M;   // M == N here
            auto at = [&](int d) {
                return (__hip_atomic_fetch_add(&cb[d], 1, __ATOMIC_RELAXED,
                        __HIP_MEMORY_SCOPE_WORKGROUP) << 3) | (int)xcd;
            };
            int t = (((bid >> 1) * 256) + tid) * 4;
            if (t + 3 < E) {
                int4 d = *(const int4*)(eiDst + t);
                int r0 = at(d.x);
                int r1 = at(d.y);
                int r2 = at(d.z);
                int r3 = at(d.w);
                *(int4*)(rank + t) = make_int4(r0, r1, r2, r3);
            } else {
                for (int e = t; e < E; ++e)
                    rank[e] = at(eiDst[e]);
            }
            return;
        }
        gemmIdx = bid >> 1;
    } else {
        gemmIdx = blockIdx.x;
    }

    const int BM = 64, BK = 32;
    __shared__ float As[2 * BM * BK];     // 16 KB, [buf][chunk-swizzled], chunk=4 floats

    int w = tid >> 6, lane = tid & 63;
    int q = lane >> 4, n16 = lane & 15;
    int m0 = gemmIdx * BM;

    auto stage = [&](int k0, int buf) {
#pragma unroll
        for (int rep = 0; rep < 2; ++rep) {
            int cb = (w * 2 + rep) * 64;          // chunk base (wave-uniform), 0..511
            int s = cb + lane;                    // chunk index
            int m = s >> 3;                       // tile row 0..63
            int kk = (s & 7) ^ (m & 7);           // XOR swizzle
            int row = m0 + m; if (row > M - 1) row = M - 1;  // clamp, never stored
            gll16(A + (size_t)row * K + k0 + kk * 4,
                  &As[buf * (BM * BK) + cb * 4]);
        }
    };

    stage(0, 0);   // async

    f32x4 acc[4];
#pragma unroll
    for (int nt = 0; nt < 4; ++nt) acc[nt] = (f32x4)(0.f);

    // per-lane W base: row n16 (+nt*16), cols q*8; L1-cached (whole W = 64*K*2 B)
    const __half* wp = Wt + (size_t)n16 * K + q * 8;

    const int T = K / BK;
    for (int kt = 0; kt < T; ++kt) {
        __syncthreads();                      // tile kt deposited
        if (kt + 1 < T) stage((kt + 1) * BK, (kt + 1) & 1);
        const float* As_ = &As[(kt & 1) * (BM * BK)];

        int ml = w * 16 + n16;
        int e0 = (2 * q) ^ (ml & 7);
        int e1 = (2 * q + 1) ^ (ml & 7);
        float4 f0 = *(const float4*)&As_[(ml * 8 + e0) * 4];
        float4 f1 = *(const float4*)&As_[(ml * 8 + e1) * 4];
        float fv[8] = {f0.x, f0.y, f0.z, f0.w, f1.x, f1.y, f1.z, f1.w};
        half8 ahi, alo;
#pragma unroll
        for (int j = 0; j < 8; ++j) {
            _Float16 hi = (_Float16)fv[j];
            ahi[j] = hi;
            alo[j] = (_Float16)(fv[j] - (float)hi);
        }
#pragma unroll
        for (int nt = 0; nt < 4; ++nt) {
            uint4 u = *(const uint4*)(wp + (size_t)(nt * 16) * K + kt * BK);
            half8 b = __builtin_bit_cast(half8, u);
            acc[nt] = __builtin_amdgcn_mfma_f32_16x16x32_f16(ahi, b, acc[nt], 0, 0, 0);
            acc[nt] = __builtin_amdgcn_mfma_f32_16x16x32_f16(alo, b, acc[nt], 0, 0, 0);
        }
        __syncthreads();
    }

    // epilogue: D[row = q*4+reg][col = n16]
#pragma unroll
    for (int reg = 0; reg < 4; ++reg) {
        int row = m0 + w * 16 + q * 4 + reg;
        if (row < M) {
            float di = SCALE ? dinv[row] : 1.0f;
#pragma unroll
            for (int nt = 0; nt < 4; ++nt)
                H[(size_t)row * NFEAT + nt * 16 + n16] =
                    __float2half(di * acc[nt][reg]);
        }
    }
}

// ---------------- FUSED: shard-merge + scan phase A + dinv + base8 -------------
// For each node i: total = sum_s counts8[s][i]; base8[i*8+s] = exclusive prefix
// over shards (placement offset for shard s); counts[i] = total (read by
// k_scan_final); dinv[i] = rsqrt(total+1); bsums[bid] = block total.
__global__ __launch_bounds__(256) void k_dinv_scan(
    const int* __restrict__ counts8, int* __restrict__ counts,
    int* __restrict__ base8, int* __restrict__ bsums,
    float* __restrict__ dinv, int n)
{
    __shared__ int red[256];
    int tid = threadIdx.x;
    int bid = blockIdx.x;
    int base0 = bid * SCAN_CHUNK + tid * 8;
    int ssum = 0;

    if (base0 + 7 < n) {
        int tot[8];
        int bv[8][8];
#pragma unroll
        for (int i = 0; i < 8; ++i) tot[i] = 0;
#pragma unroll
        for (int s = 0; s < 8; ++s) {
            const int4* p = (const int4*)(counts8 + (size_t)s * n + base0);
            int4 c0 = p[0], c1 = p[1];
            int c[8] = {c0.x, c0.y, c0.z, c0.w, c1.x, c1.y, c1.z, c1.w};
#pragma unroll
            for (int i = 0; i < 8; ++i) { bv[i][s] = tot[i]; tot[i] += c[i]; }
        }
#pragma unroll
        for (int i = 0; i < 8; ++i) {
            *(int4*)(base8 + (size_t)(base0 + i) * 8) =
                make_int4(bv[i][0], bv[i][1], bv[i][2], bv[i][3]);
            *(int4*)(base8 + (size_t)(base0 + i) * 8 + 4) =
                make_int4(bv[i][4], bv[i][5], bv[i][6], bv[i][7]);
        }
        *(int4*)(counts + base0)     = make_int4(tot[0], tot[1], tot[2], tot[3]);
        *(int4*)(counts + base0 + 4) = make_int4(tot[4], tot[5], tot[6], tot[7]);
        *(float4*)(dinv + base0) = make_float4(
            rsqrtf((float)(tot[0] + 1)), rsqrtf((float)(tot[1] + 1)),
            rsqrtf((float)(tot[2] + 1)), rsqrtf((float)(tot[3] + 1)));
        *(float4*)(dinv + base0 + 4) = make_float4(
            rsqrtf((float)(tot[4] + 1)), rsqrtf((float)(tot[5] + 1)),
            rsqrtf((float)(tot[6] + 1)), rsqrtf((float)(tot[7] + 1)));
#pragma unroll
        for (int i = 0; i < 8; ++i) ssum += tot[i];
    } else {
#pragma unroll
        for (int i = 0; i < 8; ++i) {
            int idx = base0 + i;
            if (idx < n) {
                int t = 0;
#pragma unroll
                for (int s = 0; s < 8; ++s) {
                    base8[(size_t)idx * 8 + s] = t;
                    t += counts8[(size_t)s * n + idx];
                }
                counts[idx] = t;
                dinv[idx] = rsqrtf((float)(t + 1));
                ssum += t;
            }
        }
    }

    red[tid] = ssum;
    __syncthreads();
    for (int off = 128; off; off >>= 1) {
        if (tid < off) red[tid] += red[tid + off];
        __syncthreads();
    }
    if (tid == 0) bsums[bid] = red[0];
}

__global__ void k_scan_sums(int* bsums, int nb) {
    __shared__ int ts[64];
    int tid = threadIdx.x;
    if (tid < 64) ts[tid] = (tid < nb) ? bsums[tid] : 0;
    __syncthreads();
    if (tid == 0) {
        int run = 0;
        for (int i = 0; i < nb; ++i) { int t = ts[i]; ts[i] = run; run += t; }
    }
    __syncthreads();
    if (tid < nb) bsums[tid] = ts[tid];
}

__global__ __launch_bounds__(256) void k_scan_final(const int* __restrict__ counts,
                                                    const int* __restrict__ bsums,
                                                    int* __restrict__ rowptr, int n) {
    __shared__ int ts[256];
    int tid = threadIdx.x;
    int base0 = blockIdx.x * SCAN_CHUNK + tid * 8;
    int v[8], c[8];
    int s = 0;
#pragma unroll
    for (int i = 0; i < 8; ++i) {
        int idx = base0 + i;
        c[i] = (idx < n) ? counts[idx] : 0;
        v[i] = s;
        s += c[i];
    }
    ts[tid] = s;
    __syncthreads();
    for (int off = 1; off < 256; off <<= 1) {
        int t = (tid >= off) ? ts[tid - off] : 0;
        __syncthreads();
        if (tid >= off) ts[tid] += t;
        __syncthreads();
    }
    int texcl = ts[tid] - s;
    int base = bsums[blockIdx.x] + texcl;
#pragma unroll
    for (int i = 0; i < 8; ++i) {
        int idx = base0 + i;
        if (idx < n) {
            int val = base + v[i];
            rowptr[idx] = val;
            if (idx == n - 1) rowptr[n] = val + c[i];
        }
    }
}

// ---------------- FUSED: CSR placement + deferred h *= dinv --------------------
__global__ __launch_bounds__(256) void k_build_scale(
    const int* __restrict__ ei, const int* __restrict__ rank,
    const int* __restrict__ rowptr, const int* __restrict__ base8,
    int* __restrict__ col, int E,
    __half* __restrict__ A, const float* __restrict__ dinv, int N, int gE)
{
    int bid = blockIdx.x;
    if (bid < gE) {
        int e = bid * 256 + threadIdx.x;
        if (e >= E) return;
        int src = ei[e];
        int dst = ei[(size_t)E + e];
        int r = rank[e];
        col[rowptr[dst] + base8[(size_t)dst * 8 + (r & 7)] + (r >> 3)] = src;
    } else {
        int i = (bid - gE) * 256 + threadIdx.x;   // uint4 index (8 halves)
        if (i >= N * 8) return;
        float di = dinv[i >> 3];
        uint4* p = (uint4*)A + i;
        uint4 u = *p;
        auto sc = [&](unsigned int x) {
            float2 f = __half22float2(bch(x));
            return __builtin_bit_cast(unsigned int,
                   __float22half2_rn(make_float2(f.x * di, f.y * di)));
        };
        u.x = sc(u.x); u.y = sc(u.y); u.z = sc(u.z); u.w = sc(u.w);
        *p = u;
    }
}

// ---------------- CSR gather-aggregate: 1 slot = 1 row ------------------------
template<bool FC>
__global__ __launch_bounds__(256) void k_aggr(
    const __half* __restrict__ h, const int* __restrict__ rowptr,
    const int* __restrict__ col, const float* __restrict__ dinv,
    const float* __restrict__ bias, const float* __restrict__ Wfc,
    const float* __restrict__ bfc, float* __restrict__ out, int n)
{
    __shared__ float Wl[NFEAT * 11 + 11];
    int tid = threadIdx.x;
    if (FC) {
        for (int i = tid; i < NFEAT * 11; i += 256) Wl[i] = Wfc[i];
        if (tid < 11) Wl[NFEAT * 11 + tid] = bfc[tid];
        __syncthreads();
    }
    int lane = tid & 63;
    int li = lane & 7;
    int fi = li << 3;
    int r = blockIdx.x * 32 + ((tid >> 6) << 3) + (lane >> 3);
    bool valid = r < n;

    int beg = 0, end = 0;
    if (valid) { beg = rowptr[r]; end = rowptr[r + 1]; }

    const __half* hp = h + fi;
    auto ld = [&](int src) { return *(const uint4*)(hp + (size_t)src * NFEAT); };

    float a0 = 0.f, a1 = 0.f, a2 = 0.f, a3 = 0.f,
          a4 = 0.f, a5 = 0.f, a6 = 0.f, a7 = 0.f;
    auto addu = [&](uint4 u) {
        float2 f0 = __half22float2(bch(u.x));
        float2 f1 = __half22float2(bch(u.y));
        float2 f2 = __half22float2(bch(u.z));
        float2 f3 = __half22float2(bch(u.w));
        a0 += f0.x; a1 += f0.y; a2 += f1.x; a3 += f1.y;
        a4 += f2.x; a5 += f2.y; a6 += f3.x; a7 += f3.y;
    };

    if (valid) addu(ld(r));
    int j = beg;
    for (; j + 1 < end; j += 2) {
        uint4 u0 = ld(col[j]);
        uint4 u1 = ld(col[j + 1]);
        uint4 s;
        s.x = __builtin_bit_cast(unsigned int, __hadd2(bch(u0.x), bch(u1.x)));
        s.y = __builtin_bit_cast(unsigned int, __hadd2(bch(u0.y), bch(u1.y)));
        s.z = __builtin_bit_cast(unsigned int, __hadd2(bch(u0.z), bch(u1.z)));
        s.w = __builtin_bit_cast(unsigned int, __hadd2(bch(u0.w), bch(u1.w)));
        addu(s);
    }
    if (j < end) addu(ld(col[j]));

    if (!valid) return;
    float di = dinv[r];
    float t0 = fmaxf(bias[fi + 0] + di * a0, 0.f);
    float t1 = fmaxf(bias[fi + 1] + di * a1, 0.f);
    float t2 = fmaxf(bias[fi + 2] + di * a2, 0.f);
    float t3 = fmaxf(bias[fi + 3] + di * a3, 0.f);
    float t4 = fmaxf(bias[fi + 4] + di * a4, 0.f);
    float t5 = fmaxf(bias[fi + 5] + di * a5, 0.f);
    float t6 = fmaxf(bias[fi + 6] + di * a6, 0.f);
    float t7 = fmaxf(bias[fi + 7] + di * a7, 0.f);

    if (!FC) {
        float4 lo = make_float4(t0, t1, t2, t3);
        float4 hi = make_float4(t4, t5, t6, t7);
        float* op = out + (size_t)r * NFEAT + fi;
        *(float4*)op = lo;
        *(float4*)(op + 4) = hi;
    } else {
#pragma unroll
        for (int c = 0; c < 11; ++c) {
            const float* wc = &Wl[fi * 11 + c];
            float p = t0 * wc[0] + t1 * wc[11] + t2 * wc[22] + t3 * wc[33]
                    + t4 * wc[44] + t5 * wc[55] + t6 * wc[66] + t7 * wc[77];
            p += __shfl_xor(p, 1, 64);
            p += __shfl_xor(p, 2, 64);
            p += __shfl_xor(p, 4, 64);
            if (li == 0) out[(size_t)r * 11 + c] = p + Wl[NFEAT * 11 + c];
        }
    }
}

extern "C" void kernel_launch(void* const* d_in, const int* in_sizes, int n_in,
                              void* d_out, int out_size, void* d_ws, size_t ws_size,
                              hipStream_t stream) {
    const float* x   = (const float*)d_in[0];
    const int*   ei  = (const int*)d_in[1];
    const float* W1  = (const float*)d_in[2];
    const float* b1  = (const float*)d_in[3];
    const float* W2  = (const float*)d_in[4];
    const float* b2  = (const float*)d_in[5];
    const float* Wfc = (const float*)d_in[6];
    const float* bfc = (const float*)d_in[7];
    float* out = (float*)d_out;

    const int Fin = 256;
    int N = in_sizes[0] / Fin;      // 100000
    int E = in_sizes[1] / 2;        // 1600000

    char* ws = (char*)d_ws;
    size_t off = 0;
    auto alloc = [&](size_t bytes) { void* p = ws + off; off = (off + bytes + 255) & ~(size_t)255; return p; };
    int*    counts = (int*)   alloc((size_t)N * 4);
    int*    rowptr = (int*)   alloc((size_t)(N + 1) * 4);
    float*  dinv   = (float*) alloc((size_t)N * 4);
    int*    bsums  = (int*)   alloc(64 * 4);
    int*    rank   = (int*)   alloc((size_t)E * 4);
    int*    col    = (int*)   alloc((size_t)E * 4);
    __half* Wt1    = (__half*)alloc((size_t)64 * 256 * 2);
    __half* Wt2    = (__half*)alloc((size_t)64 * 64 * 2);
    __half* A      = (__half*)alloc((size_t)N * NFEAT * 2);  // h buffer (fp16)
    float*  B      = (float*) alloc((size_t)N * NFEAT * 4);  // relu(out1) buffer

    // counts8/base8 alias B's first 6.4MB: both dead before k_aggr<false> writes B.
    int* counts8 = (int*)B;                    // [8][N] XCD-sharded degree counts
    int* base8   = (int*)B + (size_t)8 * N;    // [N][8] per-shard exclusive bases

    int gE = (E + 255) / 256;       // 6250
    int gb = (N + 63) / 64;         // 1563 (BM=64 tiles)
    int gA = (N + 31) / 32;         // 3125
    int gS = (N * 8 + 255) / 256;   // 3125 (scale, uint4 granules)
    int nb = (N + SCAN_CHUNK - 1) / SCAN_CHUNK;   // 49 <= 64

    hipMemsetAsync(counts8, 0, (size_t)8 * N * 4, stream);
    k_cvtW<<<(64 * 256 + 255) / 256, 256, 0, stream>>>(W1, Wt1, 256);
    k_cvtW<<<(64 * 64 + 255) / 256, 256, 0, stream>>>(W2, Wt2, 64);

    // FUSED: gemm1 (unscaled) + degree count/rank (XCD-sharded L2-local atomics)
    k_gemm_x<256, false, true><<<gb * 2, 256, 0, stream>>>(
        x, Wt1, nullptr, A, N, ei + E, counts8, rank, E);

    // shard-merge + scan phase A + dinv + base8
    k_dinv_scan<<<nb, 256, 0, stream>>>(counts8, counts, base8, bsums, dinv, N);
    k_scan_sums<<<1, 64, 0, stream>>>(bsums, nb);
    k_scan_final<<<nb, 256, 0, stream>>>(counts, bsums, rowptr, N);

    // FUSED: CSR placement (rank -> shard-base + local rank) + deferred h1 *= dinv
    k_build_scale<<<gE + gS, 256, 0, stream>>>(ei, rank, rowptr, base8, col, E, A, dinv, N, gE);

    // layer 1 aggregation: B = relu(b1 + dinv*(h1[r]+sum h1[col]))
    k_aggr<false><<<gA, 256, 0, stream>>>(A, rowptr, col, dinv, b1, nullptr, nullptr, B, N);

    // layer 2: h2 = fp16(dinv*(B@W2)); fused aggr+relu+FC -> out
    k_gemm_x<64, true, false><<<gb, 256, 0, stream>>>(
        B, Wt2, dinv, A, N, nullptr, nullptr, nullptr, 0);
    k_aggr<true><<<gA, 256, 0, stream>>>(A, rowptr, col, dinv, b2, Wfc, bfc, out, N);
}

// Round 3
// 327.094 us; speedup vs baseline: 1.1600x; 1.1600x over previous
//
#include <hip/hip_runtime.h>
#include <hip/hip_fp16.h>

#define NFEAT 64
#define CE 8192          // edges per histogram/scatter chunk (256 thr x 32)
#define EBUF 4608        // LDS-staged edges per bucket in k_csr (mean 4096 + 8 sigma)

typedef _Float16 half8 __attribute__((ext_vector_type(8)));
typedef float f32x4 __attribute__((ext_vector_type(4)));

// ---------------- async global->LDS helper (16B per lane, wave-uniform LDS base) ---
__device__ __forceinline__ void gll16(const float* g, float* l) {
    __builtin_amdgcn_global_load_lds(
        (const __attribute__((address_space(1))) unsigned int*)g,
        (__attribute__((address_space(3))) unsigned int*)l, 16, 0, 0);
}

__device__ __forceinline__ __half2 bch(unsigned int u) {
    return __builtin_bit_cast(__half2, u);
}

// ---------------- W transpose+convert: Wt[n][k] = fp16(W[k][n]) ----------------
__global__ void k_cvtW(const float* __restrict__ W, __half* __restrict__ Wt, int K) {
    int idx = blockIdx.x * 256 + threadIdx.x;
    if (idx >= 64 * K) return;
    int n = idx / K;
    int k = idx % K;
    Wt[idx] = __float2half(W[(size_t)k * NFEAT + n]);
}

// ---------------- FUSED: MFMA GEMM  +  per-chunk LDS histogram ------------------
// Round-2 falsified the atomic-scope theory: WRITE_SIZE was byte-identical with
// workgroup-scope XCD-sharded atomics -> global atomics on this memory execute
// memory-side with ~32B HBM write-through each (51.2MB of the 68.6MB writes).
// Fix: NO global atomics. Count blocks (bid%9==8) build a 391-bucket LDS
// histogram (bucket = dst>>8) for an 8192-edge chunk and write hist[c][bucket].
// CSR construction is finished by scan/scatter/csr kernels with LDS-only atomics.
template<int K, bool SCALE, bool CNT>
__global__ __launch_bounds__(256) void k_gemm_x(
    const float* __restrict__ A, const __half* __restrict__ Wt,
    const float* __restrict__ dinv, __half* __restrict__ H, int M,
    const int* __restrict__ eiDst, int* __restrict__ hist, int E)
{
    const int BM = 64, BK = 32;
    __shared__ float As[2 * BM * BK];     // 16 KB; reused as int[] by hist path

    int tid = threadIdx.x;
    int gemmIdx;
    if (CNT) {
        int bid = blockIdx.x;
        int nbkt = (M + 255) >> 8;
        if (bid % 9 == 8) {
            // ---- histogram path: one 8192-edge chunk, LDS-only atomics ----
            int c = bid / 9;
            int base = c * CE;
            if (base >= E) return;
            int* hb = (int*)As;
            for (int i = tid; i < nbkt; i += 256) hb[i] = 0;
            __syncthreads();
            int hi = min(base + CE, E);
            for (int e = base + tid; e < hi; e += 256)
                atomicAdd(&hb[eiDst[e] >> 8], 1);
            __syncthreads();
            for (int i = tid; i < nbkt; i += 256)
                hist[(size_t)c * nbkt + i] = hb[i];
            return;
        }
        gemmIdx = bid - bid / 9;
    } else {
        gemmIdx = blockIdx.x;
    }
    if (gemmIdx * BM >= M) return;

    int w = tid >> 6, lane = tid & 63;
    int q = lane >> 4, n16 = lane & 15;
    int m0 = gemmIdx * BM;

    auto stage = [&](int k0, int buf) {
#pragma unroll
        for (int rep = 0; rep < 2; ++rep) {
            int cb = (w * 2 + rep) * 64;          // chunk base (wave-uniform), 0..511
            int s = cb + lane;                    // chunk index
            int m = s >> 3;                       // tile row 0..63
            int kk = (s & 7) ^ (m & 7);           // XOR swizzle
            int row = m0 + m; if (row > M - 1) row = M - 1;  // clamp, never stored
            gll16(A + (size_t)row * K + k0 + kk * 4,
                  &As[buf * (BM * BK) + cb * 4]);
        }
    };

    stage(0, 0);   // async

    f32x4 acc[4];
#pragma unroll
    for (int nt = 0; nt < 4; ++nt) acc[nt] = (f32x4)(0.f);

    // per-lane W base: row n16 (+nt*16), cols q*8; L1-cached (whole W = 64*K*2 B)
    const __half* wp = Wt + (size_t)n16 * K + q * 8;

    const int T = K / BK;
    for (int kt = 0; kt < T; ++kt) {
        __syncthreads();                      // tile kt deposited
        if (kt + 1 < T) stage((kt + 1) * BK, (kt + 1) & 1);
        const float* As_ = &As[(kt & 1) * (BM * BK)];

        int ml = w * 16 + n16;
        int e0 = (2 * q) ^ (ml & 7);
        int e1 = (2 * q + 1) ^ (ml & 7);
        float4 f0 = *(const float4*)&As_[(ml * 8 + e0) * 4];
        float4 f1 = *(const float4*)&As_[(ml * 8 + e1) * 4];
        float fv[8] = {f0.x, f0.y, f0.z, f0.w, f1.x, f1.y, f1.z, f1.w};
        half8 ahi, alo;
#pragma unroll
        for (int j = 0; j < 8; ++j) {
            _Float16 hi = (_Float16)fv[j];
            ahi[j] = hi;
            alo[j] = (_Float16)(fv[j] - (float)hi);
        }
#pragma unroll
        for (int nt = 0; nt < 4; ++nt) {
            uint4 u = *(const uint4*)(wp + (size_t)(nt * 16) * K + kt * BK);
            half8 b = __builtin_bit_cast(half8, u);
            acc[nt] = __builtin_amdgcn_mfma_f32_16x16x32_f16(ahi, b, acc[nt], 0, 0, 0);
            acc[nt] = __builtin_amdgcn_mfma_f32_16x16x32_f16(alo, b, acc[nt], 0, 0, 0);
        }
        __syncthreads();
    }

    // epilogue: D[row = q*4+reg][col = n16]
#pragma unroll
    for (int reg = 0; reg < 4; ++reg) {
        int row = m0 + w * 16 + q * 4 + reg;
        if (row < M) {
            float di = SCALE ? dinv[row] : 1.0f;
#pragma unroll
            for (int nt = 0; nt < 4; ++nt)
                H[(size_t)row * NFEAT + nt * 16 + n16] =
                    __float2half(di * acc[nt][reg]);
        }
    }
}

// ---------------- scan B: per-bucket exclusive scan over chunks ----------------
// block b: hist[c][b] (c=0..nchk-1) -> exclusive prefix (in place), cntB[b]=total
__global__ __launch_bounds__(256) void k_scanB(int* __restrict__ hist,
                                               int* __restrict__ cntB,
                                               int nchk, int nbkt) {
    __shared__ int hb[256];
    int b = blockIdx.x, tid = threadIdx.x;
    int v = (tid < nchk) ? hist[(size_t)tid * nbkt + b] : 0;
    hb[tid] = v;
    __syncthreads();
    for (int off = 1; off < 256; off <<= 1) {
        int t = (tid >= off) ? hb[tid - off] : 0;
        __syncthreads();
        if (tid >= off) hb[tid] += t;
        __syncthreads();
    }
    if (tid < nchk) hist[(size_t)tid * nbkt + b] = hb[tid] - v;
    if (tid == 255) cntB[b] = hb[255];
}

// ---------------- scan C: bucket bases (bb[0..nbkt], bb[nbkt] = E) -------------
__global__ __launch_bounds__(256) void k_scanC(const int* __restrict__ cntB,
                                               int* __restrict__ bb, int nbkt) {
    __shared__ int hb[256];
    int tid = threadIdx.x;
    int i0 = 2 * tid, i1 = 2 * tid + 1;
    int a0 = (i0 < nbkt) ? cntB[i0] : 0;
    int a1 = (i1 < nbkt) ? cntB[i1] : 0;
    hb[tid] = a0 + a1;
    __syncthreads();
    for (int off = 1; off < 256; off <<= 1) {
        int t = (tid >= off) ? hb[tid - off] : 0;
        __syncthreads();
        if (tid >= off) hb[tid] += t;
        __syncthreads();
    }
    int excl = hb[tid] - (a0 + a1);
    if (i0 <= nbkt) bb[i0] = excl;
    if (i1 <= nbkt) bb[i1] = excl + a0;
}

// ---------------- scatter: edges -> bucket-ordered E2, LDS cursors -------------
__global__ __launch_bounds__(256) void k_scatter(
    const int* __restrict__ ei, const int* __restrict__ hist,
    const int* __restrict__ bb, int2* __restrict__ E2, int E, int nbkt)
{
    __shared__ int ptr[512];
    int c = blockIdx.x, tid = threadIdx.x;
    for (int i = tid; i < nbkt; i += 256)
        ptr[i] = bb[i] + hist[(size_t)c * nbkt + i];
    __syncthreads();
    int base = c * CE, hi = min(base + CE, E);
    for (int e = base + tid; e < hi; e += 256) {
        int s = ei[e];
        int d = ei[(size_t)E + e];
        int p = atomicAdd(&ptr[d >> 8], 1);
        E2[p] = make_int2(s, d);
    }
}

// ---------------- csr: per-bucket CSR build + dinv + fused A *= dinv -----------
// block b owns nodes [b*256, b*256+256) and edges [bb[b], bb[b+1]).
__global__ __launch_bounds__(256) void k_csr(
    const int2* __restrict__ E2, const int* __restrict__ bb,
    int* __restrict__ rowptr, float* __restrict__ dinv, int* __restrict__ col,
    __half* __restrict__ A, int N, int E)
{
    __shared__ int2 ebuf[EBUF];     // 36.9 KB
    __shared__ int cnt[256];
    __shared__ float dl[256];
    int b = blockIdx.x, tid = threadIdx.x;
    int e0 = bb[b], e1 = bb[b + 1], ne = e1 - e0;
    int nL = min(ne, EBUF);

    cnt[tid] = 0;
    __syncthreads();
    for (int i = tid; i < nL; i += 256) {
        int2 e = E2[e0 + i];
        ebuf[i] = e;
        atomicAdd(&cnt[e.y & 255], 1);
    }
    for (int i = nL + tid; i < ne; i += 256) {        // overflow (p ~ 0)
        int2 e = E2[e0 + i];
        atomicAdd(&cnt[e.y & 255], 1);
    }
    __syncthreads();
    int c = cnt[tid];
    dl[tid] = rsqrtf((float)(c + 1));                  // +1 self-loop
    for (int off = 1; off < 256; off <<= 1) {
        int t = (tid >= off) ? cnt[tid - off] : 0;
        __syncthreads();
        if (tid >= off) cnt[tid] += t;
        __syncthreads();
    }
    int excl = cnt[tid] - c;
    int node = b * 256 + tid;
    if (node < N) {
        rowptr[node] = e0 + excl;
        dinv[node] = dl[tid];
    }
    if (b == 0 && tid == 0) rowptr[N] = E;
    __syncthreads();
    cnt[tid] = excl;                                   // placement cursor
    __syncthreads();
    for (int i = tid; i < nL; i += 256) {
        int2 e = ebuf[i];
        int p = atomicAdd(&cnt[e.y & 255], 1);
        col[e0 + p] = e.x;
    }
    for (int i = nL + tid; i < ne; i += 256) {
        int2 e = E2[e0 + i];
        int p = atomicAdd(&cnt[e.y & 255], 1);
        col[e0 + p] = e.x;
    }

    // fused deferred scale: A[row] *= dinv[row] for this bucket's 256 rows
    for (int it = tid; it < 256 * 8; it += 256) {
        int ln = it >> 3;
        int node2 = b * 256 + ln;
        if (node2 < N) {
            float di = dl[ln];
            uint4* p = (uint4*)A + (size_t)node2 * 8 + (it & 7);
            uint4 u = *p;
            auto sc = [&](unsigned int x) {
                float2 f = __half22float2(bch(x));
                return __builtin_bit_cast(unsigned int,
                       __float22half2_rn(make_float2(f.x * di, f.y * di)));
            };
            u.x = sc(u.x); u.y = sc(u.y); u.z = sc(u.z); u.w = sc(u.w);
            *p = u;
        }
    }
}

// ---------------- CSR gather-aggregate: 1 slot = 1 row ------------------------
template<bool FC>
__global__ __launch_bounds__(256) void k_aggr(
    const __half* __restrict__ h, const int* __restrict__ rowptr,
    const int* __restrict__ col, const float* __restrict__ dinv,
    const float* __restrict__ bias, const float* __restrict__ Wfc,
    const float* __restrict__ bfc, float* __restrict__ out, int n)
{
    __shared__ float Wl[NFEAT * 11 + 11];
    int tid = threadIdx.x;
    if (FC) {
        for (int i = tid; i < NFEAT * 11; i += 256) Wl[i] = Wfc[i];
        if (tid < 11) Wl[NFEAT * 11 + tid] = bfc[tid];
        __syncthreads();
    }
    int lane = tid & 63;
    int li = lane & 7;
    int fi = li << 3;
    int r = blockIdx.x * 32 + ((tid >> 6) << 3) + (lane >> 3);
    bool valid = r < n;

    int beg = 0, end = 0;
    if (valid) { beg = rowptr[r]; end = rowptr[r + 1]; }

    const __half* hp = h + fi;
    auto ld = [&](int src) { return *(const uint4*)(hp + (size_t)src * NFEAT); };

    float a0 = 0.f, a1 = 0.f, a2 = 0.f, a3 = 0.f,
          a4 = 0.f, a5 = 0.f, a6 = 0.f, a7 = 0.f;
    auto addu = [&](uint4 u) {
        float2 f0 = __half22float2(bch(u.x));
        float2 f1 = __half22float2(bch(u.y));
        float2 f2 = __half22float2(bch(u.z));
        float2 f3 = __half22float2(bch(u.w));
        a0 += f0.x; a1 += f0.y; a2 += f1.x; a3 += f1.y;
        a4 += f2.x; a5 += f2.y; a6 += f3.x; a7 += f3.y;
    };

    if (valid) addu(ld(r));
    int j = beg;
    for (; j + 1 < end; j += 2) {
        uint4 u0 = ld(col[j]);
        uint4 u1 = ld(col[j + 1]);
        uint4 s;
        s.x = __builtin_bit_cast(unsigned int, __hadd2(bch(u0.x), bch(u1.x)));
        s.y = __builtin_bit_cast(unsigned int, __hadd2(bch(u0.y), bch(u1.y)));
        s.z = __builtin_bit_cast(unsigned int, __hadd2(bch(u0.z), bch(u1.z)));
        s.w = __builtin_bit_cast(unsigned int, __hadd2(bch(u0.w), bch(u1.w)));
        addu(s);
    }
    if (j < end) addu(ld(col[j]));

    if (!valid) return;
    float di = dinv[r];
    float t0 = fmaxf(bias[fi + 0] + di * a0, 0.f);
    float t1 = fmaxf(bias[fi + 1] + di * a1, 0.f);
    float t2 = fmaxf(bias[fi + 2] + di * a2, 0.f);
    float t3 = fmaxf(bias[fi + 3] + di * a3, 0.f);
    float t4 = fmaxf(bias[fi + 4] + di * a4, 0.f);
    float t5 = fmaxf(bias[fi + 5] + di * a5, 0.f);
    float t6 = fmaxf(bias[fi + 6] + di * a6, 0.f);
    float t7 = fmaxf(bias[fi + 7] + di * a7, 0.f);

    if (!FC) {
        float4 lo = make_float4(t0, t1, t2, t3);
        float4 hi = make_float4(t4, t5, t6, t7);
        float* op = out + (size_t)r * NFEAT + fi;
        *(float4*)op = lo;
        *(float4*)(op + 4) = hi;
    } else {
#pragma unroll
        for (int c = 0; c < 11; ++c) {
            const float* wc = &Wl[fi * 11 + c];
            float p = t0 * wc[0] + t1 * wc[11] + t2 * wc[22] + t3 * wc[33]
                    + t4 * wc[44] + t5 * wc[55] + t6 * wc[66] + t7 * wc[77];
            p += __shfl_xor(p, 1, 64);
            p += __shfl_xor(p, 2, 64);
            p += __shfl_xor(p, 4, 64);
            if (li == 0) out[(size_t)r * 11 + c] = p + Wl[NFEAT * 11 + c];
        }
    }
}

extern "C" void kernel_launch(void* const* d_in, const int* in_sizes, int n_in,
                              void* d_out, int out_size, void* d_ws, size_t ws_size,
                              hipStream_t stream) {
    const float* x   = (const float*)d_in[0];
    const int*   ei  = (const int*)d_in[1];
    const float* W1  = (const float*)d_in[2];
    const float* b1  = (const float*)d_in[3];
    const float* W2  = (const float*)d_in[4];
    const float* b2  = (const float*)d_in[5];
    const float* Wfc = (const float*)d_in[6];
    const float* bfc = (const float*)d_in[7];
    float* out = (float*)d_out;

    const int Fin = 256;
    int N = in_sizes[0] / Fin;      // 100000
    int E = in_sizes[1] / 2;        // 1600000

    char* ws = (char*)d_ws;
    size_t off = 0;
    auto alloc = [&](size_t bytes) { void* p = ws + off; off = (off + bytes + 255) & ~(size_t)255; return p; };
    int*    rowptr = (int*)   alloc((size_t)(N + 1) * 4);
    float*  dinv   = (float*) alloc((size_t)N * 4);
    int*    col    = (int*)   alloc((size_t)E * 4);
    __half* Wt1    = (__half*)alloc((size_t)64 * 256 * 2);
    __half* Wt2    = (__half*)alloc((size_t)64 * 64 * 2);
    __half* A      = (__half*)alloc((size_t)N * NFEAT * 2);  // h buffer (fp16)
    float*  B      = (float*) alloc((size_t)N * NFEAT * 4);  // relu(out1) buffer

    int NBKT = (N + 255) >> 8;                  // 391 buckets of 256 nodes
    int NCHK = (E + CE - 1) / CE;               // 196 chunks of 8192 edges

    // E2/hist/bb/cntB alias B (all dead before k_aggr<false> writes B)
    int2* E2   = (int2*)B;                      // [E] bucket-ordered (src,dst)
    int*  hist = (int*)B + (size_t)2 * E;       // [NCHK][NBKT]
    int*  bb   = hist + (size_t)NCHK * NBKT;    // [NBKT+1] bucket bases
    int*  cntB = bb + NBKT + 1;                 // [NBKT] bucket totals

    int gE2 = NCHK;                 // scatter blocks
    int gb  = (N + 63) / 64;        // 1563 GEMM tiles
    int gA  = (N + 31) / 32;        // 3125
    // fused grid: count bids at %9==8; gemm slots = 8/9 of grid
    int g9  = 9 * max(NCHK, (gb + 7) / 8);      // 1764

    k_cvtW<<<(64 * 256 + 255) / 256, 256, 0, stream>>>(W1, Wt1, 256);
    k_cvtW<<<(64 * 64 + 255) / 256, 256, 0, stream>>>(W2, Wt2, 64);

    // FUSED: gemm1 (unscaled) + per-chunk LDS histograms (no global atomics)
    k_gemm_x<256, false, true><<<g9, 256, 0, stream>>>(
        x, Wt1, nullptr, A, N, ei + E, hist, E);

    // CSR build: chunk-scan -> bucket-base scan -> scatter -> per-bucket CSR
    k_scanB<<<NBKT, 256, 0, stream>>>(hist, cntB, NCHK, NBKT);
    k_scanC<<<1, 256, 0, stream>>>(cntB, bb, NBKT);
    k_scatter<<<gE2, 256, 0, stream>>>(ei, hist, bb, E2, E, NBKT);
    k_csr<<<NBKT, 256, 0, stream>>>(E2, bb, rowptr, dinv, col, A, N, E);

    // layer 1 aggregation: B = relu(b1 + dinv*(h1[r]+sum h1[col]))
    k_aggr<false><<<gA, 256, 0, stream>>>(A, rowptr, col, dinv, b1, nullptr, nullptr, B, N);

    // layer 2: h2 = fp16(dinv*(B@W2)); fused aggr+relu+FC -> out
    k_gemm_x<64, true, false><<<gb, 256, 0, stream>>>(
        B, Wt2, dinv, A, N, nullptr, nullptr, 0);
    k_aggr<true><<<gA, 256, 0, stream>>>(A, rowptr, col, dinv, b2, Wfc, bfc, out, N);
}